// Round 2
// baseline (249.377 us; speedup 1.0000x reference)
//
#include <hip/hip_runtime.h>

// GRU: B=8192 chains, T=512 steps, IN=5, H=7, fused heads.
// R8 (from R7 @127us kernel, VALUBusy 60%, occ 18.4% = 2 waves/SIMD):
// dual-chain ILP. Each 16-lane group now advances TWO independent batches
// (a,b); every dependent op of chain a is pair-issued with chain b's, so
// chain b fills chain a's latency bubbles (serial matvec->sigmoid->tanh
// chain, quarter-rate transcendentals). Weights fully shared. Blocks go
// 256thr/16batch -> 128thr/16batch (8 groups x 2 chains), grid stays 512,
// waves 2048 -> 1024 = 1/SIMD (ILP replaces TLP).
// R7 (verified): head rows (W_m x3, W_r) folded into pad lanes l=7,15 of the
// packed whh pk_fma rotation; head value = accH of those lanes.
// Layout (R4/R5, verified): 16 lanes/batch, lane l: slot0 = r row (l<8) /
// z row (l>=8), slot1 = n row (both halves); one sigmoid/lane + ror:8 swap;
// heads deferred 1 step, riding the same rotation.
// DPP anchor (R3-R7 passed): row_ror:N dst[n]=src[(n-N)mod16]; position i
// holds unit (l-i)&7; weight k=(j-i)&7, k==7 -> 0 (pad killed).
// LDS banks: slot s=2g(+1), XSTR=164 -> dword bank (8g[+4]+w)%32: b128 reads
// broadcast within group, disjoint 4-dword ranges across the 4 groups/wave.

namespace {
constexpr int Bn = 8192;
constexpr int Tn = 512;
constexpr int INn = 5;
constexpr int Hn = 7;
constexpr int TILE = 32;
constexpr int NTILE = Tn / TILE;         // 16
constexpr int BPB = 16;                  // batches per block (8 groups x 2)
constexpr int XSTR = 164;                // padded floats/batch in LDS
constexpr long long OFF_OR = (long long)Bn * Tn * 3;
constexpr long long OFF_HL = OFF_OR + (long long)Bn * Tn;
constexpr float LOG2E = 1.44269504088896340736f;
}

typedef float v2f __attribute__((ext_vector_type(2)));

__device__ __forceinline__ v2f pk_fma(v2f a, v2f b, v2f c) {
    return __builtin_elementwise_fma(a, b, c);
}
__device__ __forceinline__ v2f splat2(float x) { return (v2f){x, x}; }

__device__ __forceinline__ float fast_tanh(float x) {
    float e = __builtin_amdgcn_exp2f(-2.0f * LOG2E * x);
    return __builtin_amdgcn_rcpf(1.0f + e) * 2.0f - 1.0f;
}

template<int CTRL>
__device__ __forceinline__ float dppf(float v) {
    int r = __builtin_amdgcn_update_dpp(0, __builtin_bit_cast(int, v),
                                        CTRL, 0xF, 0xF, true);
    return __builtin_bit_cast(float, r);
}

__global__ __launch_bounds__(128, 1) void gru_fused_kernel(
    const float* __restrict__ x,     // [B, T, IN]
    const float* __restrict__ W_ih,  // [21, 5]
    const float* __restrict__ W_hh,  // [21, 7]
    const float* __restrict__ b_ih,  // [21]
    const float* __restrict__ b_hh,  // [21]
    const float* __restrict__ W_h0,  // [7, 1]
    const float* __restrict__ W_m,   // [3, 7]
    const float* __restrict__ b_m,   // [3]
    const float* __restrict__ W_r,   // [1, 7]
    const float* __restrict__ b_r,   // [1]
    float* __restrict__ out)
{
    __shared__ float lds_x[2][BPB * XSTR];   // 2 x 10.25 KB

    const int tid  = threadIdx.x;
    const int l    = tid & 15;           // lane within 16-lane batch group
    const int j    = l & 7;              // hidden-unit slot (7 = pad/head lane)
    const int g    = tid >> 4;           // group slot in block (0..7)
    const int ba   = blockIdx.x * BPB + 2 * g;     // chain a batch
    const int bb   = ba + 1;                       // chain b batch
    const int jj   = (j < 7) ? j : 6;
    const bool lo8 = ((l & 8) == 0);
    const bool hl  = (j == 7);           // head lanes: l == 7 and l == 15

    // ---- rotated, packed weights (shared by both chains) ----
    const int row0 = lo8 ? jj : (Hn + jj);
    const int row1 = 2 * Hn + jj;

    v2f whh_rot[8];
    #pragma unroll
    for (int i = 0; i < 8; ++i) {
        const int k = (j - i) & 7;
        if (k < 7) {
            if (hl) {
                const float w0 = lo8 ? W_m[0 * Hn + k] : W_m[2 * Hn + k];
                const float w1 = lo8 ? W_m[1 * Hn + k] : W_r[k];
                whh_rot[i] = (v2f){w0, w1};
            } else {
                whh_rot[i] = (v2f){W_hh[row0 * Hn + k], W_hh[row1 * Hn + k]};
            }
        } else {
            whh_rot[i] = (v2f){0.0f, 0.0f};
        }
    }
    v2f wih01[INn];
    #pragma unroll
    for (int i = 0; i < INn; ++i)
        wih01[i] = hl ? (v2f){0.0f, 0.0f}
                      : (v2f){W_ih[row0 * INn + i], W_ih[row1 * INn + i]};
    const v2f biasH = hl ? (lo8 ? (v2f){b_m[0], b_m[1]}
                                : (v2f){b_m[2], b_r[0]})
                         : (v2f){b_hh[row0], b_hh[row1]};
    const v2f biasP = hl ? (v2f){0.0f, 0.0f}
                         : (v2f){b_ih[row0], b_ih[row1]};

    float ha = W_h0[jj];
    float hb = ha;

    const float* xap = x + (long long)ba * (Tn * INn);
    const float* xbp = x + (long long)bb * (Tn * INn);

    // deferred-head store pointers (index s-1 at step s), per chain
    float* oma  = out + (long long)ba * (Tn * 3);
    float* orra = out + OFF_OR + (long long)ba * Tn;
    float* omb  = out + (long long)bb * (Tn * 3);
    float* orrb = out + OFF_OR + (long long)bb * Tn;
    float* hp0a = oma - 3 + (lo8 ? 0 : 2);
    float* hp1a = lo8 ? (oma - 2) : (orra - 1);
    float* hp0b = omb - 3 + (lo8 ? 0 : 2);
    float* hp1b = lo8 ? (omb - 2) : (orrb - 1);
    const int hs1 = lo8 ? 3 : 1;

    // ---- prologue: stage tile 0 (160 floats = 80 float2 per batch) ----
    float2 sta[5], stb[5];
    #pragma unroll
    for (int i = 0; i < 5; ++i) {
        sta[i] = *(const float2*)(xap + 2 * (l + 16 * i));
        stb[i] = *(const float2*)(xbp + 2 * (l + 16 * i));
    }

    int cur = 0;
    for (int tl = 0; tl < NTILE; ++tl) {
        #pragma unroll
        for (int i = 0; i < 5; ++i) {
            *(float2*)&lds_x[cur][(2 * g) * XSTR + 2 * (l + 16 * i)] = sta[i];
            *(float2*)&lds_x[cur][(2 * g + 1) * XSTR + 2 * (l + 16 * i)] = stb[i];
        }
        __syncthreads();

        if (tl + 1 < NTILE) {
            const float* srca = xap + (tl + 1) * (TILE * INn);
            const float* srcb = xbp + (tl + 1) * (TILE * INn);
            #pragma unroll
            for (int i = 0; i < 5; ++i) {
                sta[i] = *(const float2*)(srca + 2 * (l + 16 * i));
                stb[i] = *(const float2*)(srcb + 2 * (l + 16 * i));
            }
        }

        // x for this tile as 8 chunks of 4 steps (20 floats = 5 float4),
        // register double-buffered per chain.
        const float4* xqa = (const float4*)&lds_x[cur][(2 * g) * XSTR];
        const float4* xqb = (const float4*)&lds_x[cur][(2 * g + 1) * XSTR];
        float4 bufa[2][5], bufb[2][5];
        #pragma unroll
        for (int k = 0; k < 5; ++k) { bufa[0][k] = xqa[k]; bufb[0][k] = xqb[k]; }

        #pragma unroll
        for (int c = 0; c < 8; ++c) {
            if (c < 7) {
                #pragma unroll
                for (int k = 0; k < 5; ++k) {
                    bufa[(c + 1) & 1][k] = xqa[(c + 1) * 5 + k];
                    bufb[(c + 1) & 1][k] = xqb[(c + 1) * 5 + k];
                }
            }
            const float* xaf = (const float*)bufa[c & 1];
            const float* xbf = (const float*)bufb[c & 1];

            #pragma unroll
            for (int ss = 0; ss < 4; ++ss) {
                const int tt = c * 4 + ss;

                // systolic rotation, pair-issued for chains a and b
                v2f aA = biasH, aB = (v2f){0.0f, 0.0f};
                v2f bA = biasH, bB = (v2f){0.0f, 0.0f};
                aA = pk_fma(whh_rot[0], splat2(ha), aA);
                bA = pk_fma(whh_rot[0], splat2(hb), bA);
                {
                    float t0 = dppf<0x121>(ha);
                    float u0 = dppf<0x121>(hb);
                    aB = pk_fma(whh_rot[1], splat2(t0), aB);
                    bB = pk_fma(whh_rot[1], splat2(u0), bB);
                    float t1 = dppf<0x122>(ha);
                    float u1 = dppf<0x122>(hb);
                    aA = pk_fma(whh_rot[2], splat2(t1), aA);
                    bA = pk_fma(whh_rot[2], splat2(u1), bA);
                    float t2 = dppf<0x123>(ha);
                    float u2 = dppf<0x123>(hb);
                    aB = pk_fma(whh_rot[3], splat2(t2), aB);
                    bB = pk_fma(whh_rot[3], splat2(u2), bB);
                    float t3 = dppf<0x124>(ha);
                    float u3 = dppf<0x124>(hb);
                    aA = pk_fma(whh_rot[4], splat2(t3), aA);
                    bA = pk_fma(whh_rot[4], splat2(u3), bA);
                    float t4 = dppf<0x125>(ha);
                    float u4 = dppf<0x125>(hb);
                    aB = pk_fma(whh_rot[5], splat2(t4), aB);
                    bB = pk_fma(whh_rot[5], splat2(u4), bB);
                    float t5 = dppf<0x126>(ha);
                    float u5 = dppf<0x126>(hb);
                    aA = pk_fma(whh_rot[6], splat2(t5), aA);
                    bA = pk_fma(whh_rot[6], splat2(u5), bA);
                    float t6 = dppf<0x127>(ha);
                    float u6 = dppf<0x127>(hb);
                    aB = pk_fma(whh_rot[7], splat2(t6), aB);
                    bB = pk_fma(whh_rot[7], splat2(u6), bB);
                }
                v2f accHa = aA + aB;             // matvec (g0,g1); heads on hl
                v2f accHb = bA + bB;

                // input projection (zeroed on head lanes)
                v2f accPa = biasP, accPb = biasP;
                #pragma unroll
                for (int i = 0; i < INn; ++i) {
                    accPa = pk_fma(wih01[i], splat2(xaf[5 * ss + i]), accPa);
                    accPb = pk_fma(wih01[i], splat2(xbf[5 * ss + i]), accPb);
                }

                // deferred head(h_t) -> index t-1 (guard folds away for tt>0)
                if ((tl > 0 || tt > 0) && hl) {
                    *hp0a = accHa[0];
                    *hp1a = accHa[1];
                    *hp0b = accHb[0];
                    *hp1b = accHb[1];
                }
                hp0a += 3; hp1a += hs1;
                hp0b += 3; hp1b += hs1;

                // gates, pair-issued (head lanes: bounded garbage, unused)
                float ea = __builtin_amdgcn_exp2f(-LOG2E * (accHa[0] + accPa[0]));
                float eb = __builtin_amdgcn_exp2f(-LOG2E * (accHb[0] + accPb[0]));
                float sa = __builtin_amdgcn_rcpf(1.0f + ea);
                float sb = __builtin_amdgcn_rcpf(1.0f + eb);
                float sva = dppf<0x128>(sa);     // row_ror:8 half-swap
                float svb = dppf<0x128>(sb);
                float rva = lo8 ? sa : sva;
                float rvb = lo8 ? sb : svb;
                float zva = lo8 ? sva : sa;
                float zvb = lo8 ? svb : sb;
                float na = fast_tanh(fmaf(rva, accHa[1], accPa[1]));
                float nb = fast_tanh(fmaf(rvb, accHb[1], accPb[1]));
                ha = na + zva * (ha - na);       // (1-z)*n + z*h
                hb = nb + zvb * (hb - nb);
            }
        }
        cur ^= 1;
    }

    // epilogue: head of final h (one more rotation), stored at index T-1
    {
        v2f aA = biasH, aB = (v2f){0.0f, 0.0f};
        v2f bA = biasH, bB = (v2f){0.0f, 0.0f};
        aA = pk_fma(whh_rot[0], splat2(ha), aA);
        bA = pk_fma(whh_rot[0], splat2(hb), bA);
        aB = pk_fma(whh_rot[1], splat2(dppf<0x121>(ha)), aB);
        bB = pk_fma(whh_rot[1], splat2(dppf<0x121>(hb)), bB);
        aA = pk_fma(whh_rot[2], splat2(dppf<0x122>(ha)), aA);
        bA = pk_fma(whh_rot[2], splat2(dppf<0x122>(hb)), bA);
        aB = pk_fma(whh_rot[3], splat2(dppf<0x123>(ha)), aB);
        bB = pk_fma(whh_rot[3], splat2(dppf<0x123>(hb)), bB);
        aA = pk_fma(whh_rot[4], splat2(dppf<0x124>(ha)), aA);
        bA = pk_fma(whh_rot[4], splat2(dppf<0x124>(hb)), bA);
        aB = pk_fma(whh_rot[5], splat2(dppf<0x125>(ha)), aB);
        bB = pk_fma(whh_rot[5], splat2(dppf<0x125>(hb)), bB);
        aA = pk_fma(whh_rot[6], splat2(dppf<0x126>(ha)), aA);
        bA = pk_fma(whh_rot[6], splat2(dppf<0x126>(hb)), bA);
        aB = pk_fma(whh_rot[7], splat2(dppf<0x127>(ha)), aB);
        bB = pk_fma(whh_rot[7], splat2(dppf<0x127>(hb)), bB);
        v2f accHa = aA + aB;
        v2f accHb = bA + bB;
        if (hl) {
            *hp0a = accHa[0];
            *hp1a = accHa[1];
            *hp0b = accHb[0];
            *hp1b = accHb[1];
        }
    }

    // h_last: [1, B, H] — chain a from lanes 0-6, chain b from mirror lanes 8-14
    if (l < Hn) out[OFF_HL + (long long)ba * Hn + l] = ha;
    if (l >= 8 && l < 8 + Hn) out[OFF_HL + (long long)bb * Hn + (l - 8)] = hb;
}

extern "C" void kernel_launch(void* const* d_in, const int* in_sizes, int n_in,
                              void* d_out, int out_size, void* d_ws, size_t ws_size,
                              hipStream_t stream) {
    const float* x    = (const float*)d_in[0];
    // d_in[1] = batch_size (scalar), unused — B compiled in
    const float* W_ih = (const float*)d_in[2];
    const float* W_hh = (const float*)d_in[3];
    const float* b_ih = (const float*)d_in[4];
    const float* b_hh = (const float*)d_in[5];
    const float* W_h0 = (const float*)d_in[6];
    const float* W_m  = (const float*)d_in[7];
    const float* b_m  = (const float*)d_in[8];
    const float* W_r  = (const float*)d_in[9];
    const float* b_r  = (const float*)d_in[10];
    float* out = (float*)d_out;

    dim3 grid(Bn / BPB);  // 512 blocks
    dim3 block(128);      // 8 groups x 16 lanes, 2 chains per group
    gru_fused_kernel<<<grid, block, 0, stream>>>(x, W_ih, W_hh, b_ih, b_hh,
                                                 W_h0, W_m, b_m, W_r, b_r, out);
}